// Round 16
// baseline (451.542 us; speedup 1.0000x reference)
//
#include <hip/hip_runtime.h>
#include <hip/hip_bf16.h>
#include <math.h>

#define NROWS 8192
#define DDIM  1024
#define BT    128
#define NBLK  (NROWS / BT)
#define BM    256
#define NBLK2 (NROWS / BM)
#define MARGIN 0.3f
#define INV1024 0.0009765625f

typedef __attribute__((ext_vector_type(4))) float  f32x4;
typedef __attribute__((ext_vector_type(8))) __bf16 bf16x8;
typedef __attribute__((ext_vector_type(4))) int    i32x4;
typedef __attribute__((ext_vector_type(8))) int    i32x8;

__device__ __forceinline__ unsigned f2bf_bits(float f) {
  unsigned u = __float_as_uint(f);
  u += 0x7fffu + ((u >> 16) & 1u);   // RNE
  return u >> 16;
}

// fp4 e2m1 quantize of u (|u| up to ~6, saturating): 3-bit magnitude code is
// monotonic over levels {0,0.5,1,1.5,2,3,4,6} -> compare ladder.
__device__ __forceinline__ unsigned q4(float u) {
  float a = fabsf(u);
  unsigned c = (unsigned)(a > 0.25f) + (unsigned)(a > 0.75f) + (unsigned)(a > 1.25f)
             + (unsigned)(a > 1.75f) + (unsigned)(a > 2.5f)  + (unsigned)(a > 3.5f)
             + (unsigned)(a > 5.0f);
  return c | ((__float_as_uint(u) >> 28) & 8u);   // sign -> bit 3
}

// ============================ FAST PATH (MX-fp4) ============================
// Kernel A: row-norm + fp4 e2m1 quantize of 32*xn (row-major, 512 B/row);
// zeroes rowsum/colsum.
__global__ __launch_bounds__(256) void normconv4_kernel(const float* __restrict__ x,
                                                        const float* __restrict__ y,
                                                        unsigned short* __restrict__ xq4,
                                                        unsigned short* __restrict__ yq4,
                                                        float* __restrict__ zero_base) {
  if (blockIdx.x < 16) {  // 16 blk * 256 thr * float4 = 16384 floats (rowsum+colsum)
    ((float4*)zero_base)[blockIdx.x * 256 + threadIdx.x] = (float4){0.f, 0.f, 0.f, 0.f};
  }
  int wid  = blockIdx.x * 4 + (threadIdx.x >> 6);   // one wave per row
  int lane = threadIdx.x & 63;
  bool isx = (wid < NROWS);
  const float* src = isx ? x : y;
  unsigned short* dst = isx ? xq4 : yq4;
  int row = isx ? wid : (wid - NROWS);
  const float4* p = (const float4*)(src + (size_t)row * DDIM);
  float4 v[4];
  float s = 0.f;
#pragma unroll
  for (int a = 0; a < 4; ++a) {
    v[a] = p[a * 64 + lane];
    s = fmaf(v[a].x, v[a].x, s); s = fmaf(v[a].y, v[a].y, s);
    s = fmaf(v[a].z, v[a].z, s); s = fmaf(v[a].w, v[a].w, s);
  }
#pragma unroll
  for (int m = 1; m < 64; m <<= 1) s += __shfl_xor(s, m, 64);
  float inv = 32.0f / fmaxf(sqrtf(s), 1e-8f);
  unsigned short* drow = dst + (size_t)row * 256;  // 512 B/row as ushort
#pragma unroll
  for (int a = 0; a < 4; ++a) {
    unsigned n0 = q4(v[a].x * inv), n1 = q4(v[a].y * inv);
    unsigned n2 = q4(v[a].z * inv), n3 = q4(v[a].w * inv);
    drow[a * 64 + lane] = (unsigned short)(n0 | (n1 << 4) | (n2 << 8) | (n3 << 12));
  }
}

// Kernel B: MX-fp4 GEMM, R15 == R14 schedule with ONE change:
// __launch_bounds__(512, 2) -> (512, 1). R14's counters showed VGPR_Count=112
// (< the 128 needed for acc[8][4] alone) + WRITE_SIZE=2.36 GB + 86% HBM:
// the allocator budgeted for ~4 waves/SIMD and SPILLED THE ACCUMULATOR to
// scratch -- the kernel measured its own spill traffic, not the schedule.
// (512,1) grants the full 256-VGPR/wave budget; needed ~210 -> no spill.
// Schedule (unchanged, correctness proven by R14's absmax=0): 256x256 tile,
// 8 waves (2Mx4N), per K-tile 4 phases of {2xA ds_read (+4xB at p0) | 1 DMA
// issue -> barrier -> setprio(1) -> 8 MFMA -> setprio(0) -> [p3: counted
// vmcnt] -> barrier}; 3 LDS buffers (98 KB), depth-2 DMA pipeline,
// vmcnt(4) retires tile t+1's DMAs while t+2's ride.
__global__ __launch_bounds__(512, 1) void gemm_mx4_kernel(const unsigned char* __restrict__ xq4,
                                                          const unsigned char* __restrict__ yq4,
                                                          float* __restrict__ rowsum,
                                                          float* __restrict__ colsum,
                                                          float* __restrict__ diagv) {
  __shared__ alignas(16) unsigned char As[3][BM * 64];  // 3 x 16 KB
  __shared__ alignas(16) unsigned char Bs[3][BM * 64];  // 3 x 16 KB
  __shared__ float red_row[BM];
  __shared__ float red_col[BM];

  const int tid  = threadIdx.x;
  const int bi   = blockIdx.y;
  const int bj   = blockIdx.x;
  const int lane = tid & 63;
  const int wave = tid >> 6;            // 0..7
  const int wr   = wave >> 2, wc = wave & 3;   // 2 x 4 wave grid
  const int quad = lane >> 4, l15 = lane & 15;

  if (tid < BM) red_row[tid] = 0.f; else red_col[tid - BM] = 0.f;

  // staging (R10-proven): 1024-B DMA covers 16 rows x 64 B; lane l -> local
  // row (l>>2), physical group (l&3); SOURCE logical group (l&3)^((l>>3)&3).
  const int r_l = lane >> 2;
  const int cg  = (lane & 3) ^ ((lane >> 3) & 3);
  const unsigned char* ga = xq4 + (size_t)(bi * BM + wave * 32 + r_l) * 512 + cg * 16;
  const unsigned char* gb = yq4 + (size_t)(bj * BM + wave * 32 + r_l) * 512 + cg * 16;

#define DMA_A(buf, a, kb)                                                       \
  __builtin_amdgcn_global_load_lds(                                             \
      (const __attribute__((address_space(1))) unsigned int*)(ga + (size_t)(a) * 16 * 512 + (kb)), \
      (__attribute__((address_space(3))) unsigned int*)&As[buf][(wave * 32 + (a) * 16) * 64], \
      16, 0, 0)
#define DMA_B(buf, a, kb)                                                       \
  __builtin_amdgcn_global_load_lds(                                             \
      (const __attribute__((address_space(1))) unsigned int*)(gb + (size_t)(a) * 16 * 512 + (kb)), \
      (__attribute__((address_space(3))) unsigned int*)&Bs[buf][(wave * 32 + (a) * 16) * 64], \
      16, 0, 0)

  f32x4 acc[8][4];
#pragma unroll
  for (int i = 0; i < 8; ++i)
#pragma unroll
    for (int j = 0; j < 4; ++j) acc[i][j] = (f32x4){0.f, 0.f, 0.f, 0.f};

  const int pg = (quad ^ ((l15 >> 1) & 3)) * 16;   // physical 16B-group offset

  // prologue: tile0 -> buf0, tile1 -> buf1 (8 DMAs); retire tile0's 4 only.
  DMA_A(0, 0, 0);  DMA_A(0, 1, 0);  DMA_B(0, 0, 0);  DMA_B(0, 1, 0);
  DMA_A(1, 0, 64); DMA_A(1, 1, 64); DMA_B(1, 0, 64); DMA_B(1, 1, 64);
  asm volatile("s_waitcnt vmcnt(4) lgkmcnt(0)" ::: "memory");
  __builtin_amdgcn_s_barrier();

#pragma unroll
  for (int t = 0; t < 8; ++t) {
    const int cur = t % 3;
    const int nb  = (t + 2) % 3;
    const int kb2 = (t + 2) * 64;
    i32x4 b4[4];
#pragma unroll
    for (int p = 0; p < 4; ++p) {
      // phase ds_reads: A rows m=2p,2p+1 (+ all 4 B frags at p0)
      i32x4 a0 = *(const i32x4*)&As[cur][(wr * 128 + (2 * p) * 16 + l15) * 64 + pg];
      i32x4 a1 = *(const i32x4*)&As[cur][(wr * 128 + (2 * p + 1) * 16 + l15) * 64 + pg];
      if (p == 0) {
#pragma unroll
        for (int n = 0; n < 4; ++n)
          b4[n] = *(const i32x4*)&Bs[cur][(wc * 64 + n * 16 + l15) * 64 + pg];
      }
      // stage 1 DMA of tile t+2 per phase (depth-2 pipeline)
      if (t < 6) {
        if      (p == 0) DMA_A(nb, 0, kb2);
        else if (p == 1) DMA_A(nb, 1, kb2);
        else if (p == 2) DMA_B(nb, 0, kb2);
        else             DMA_B(nb, 1, kb2);
      }
      __builtin_amdgcn_s_barrier();
      __builtin_amdgcn_s_setprio(1);
      i32x8 af0 = (i32x8){a0.x, a0.y, a0.z, a0.w, 0, 0, 0, 0};
      i32x8 af1 = (i32x8){a1.x, a1.y, a1.z, a1.w, 0, 0, 0, 0};
#pragma unroll
      for (int n = 0; n < 4; ++n) {
        i32x8 bf = (i32x8){b4[n].x, b4[n].y, b4[n].z, b4[n].w, 0, 0, 0, 0};
        acc[2 * p][n] = __builtin_amdgcn_mfma_scale_f32_16x16x128_f8f6f4(
            af0, bf, acc[2 * p][n], 4, 4, 0, 0x7F7F7F7F, 0, 0x7F7F7F7F);
        acc[2 * p + 1][n] = __builtin_amdgcn_mfma_scale_f32_16x16x128_f8f6f4(
            af1, bf, acc[2 * p + 1][n], 4, 4, 0, 0x7F7F7F7F, 0, 0x7F7F7F7F);
      }
      __builtin_amdgcn_s_setprio(0);
      if (p == 3) {
        // counted: retire tile t+1's 4 DMAs (oldest); keep tile t+2's riding.
        if (t < 6)       asm volatile("s_waitcnt vmcnt(4)" ::: "memory");
        else if (t == 6) asm volatile("s_waitcnt vmcnt(0)" ::: "memory");
        // t==7: nothing outstanding
      }
      __builtin_amdgcn_s_barrier();
    }
  }
#undef DMA_A
#undef DMA_B

  __syncthreads();   // red_* init + all LDS traffic settled before epilogue

  // ---- epilogue (R1-validated frag mapping: row=quad*4+r, col=l15) --------
  // diag: global row==col => frag-aligned n = wr*8 - wc*4 + m, and l15==quad*4+r
  if (bi == bj && (l15 >> 2) == quad) {
    int r = l15 & 3;
#pragma unroll
    for (int m = 0; m < 8; ++m) {
      int nd = wr * 8 - wc * 4 + m;
      if (nd >= 0 && nd < 4)
        diagv[bi * BM + wr * 128 + m * 16 + l15] = acc[m][nd][r] * INV1024;
    }
  }

  float racc[8][4];
  float cacc[4];
#pragma unroll
  for (int i = 0; i < 8; ++i)
#pragma unroll
    for (int j = 0; j < 4; ++j) racc[i][j] = 0.f;
#pragma unroll
  for (int j = 0; j < 4; ++j) cacc[j] = 0.f;
#pragma unroll
  for (int m = 0; m < 8; ++m)
#pragma unroll
    for (int n = 0; n < 4; ++n) {
      f32x4 v = acc[m][n];
#pragma unroll
      for (int r = 0; r < 4; ++r) {
        float e = __expf(v[r] * INV1024);
        racc[m][r] += e;
        cacc[n]    += e;
      }
    }
  // row partials: reduce over l15 (cols) via masks 1..8
#pragma unroll
  for (int msk = 1; msk <= 8; msk <<= 1)
#pragma unroll
    for (int m = 0; m < 8; ++m)
#pragma unroll
      for (int r = 0; r < 4; ++r) racc[m][r] += __shfl_xor(racc[m][r], msk, 64);
  if (l15 == 0)
#pragma unroll
    for (int m = 0; m < 8; ++m)
#pragma unroll
      for (int r = 0; r < 4; ++r)
        atomicAdd(&red_row[wr * 128 + m * 16 + quad * 4 + r], racc[m][r]);
  // col partials: reduce over quad (rows) via masks 16,32
#pragma unroll
  for (int msk = 16; msk <= 32; msk <<= 1)
#pragma unroll
    for (int n = 0; n < 4; ++n) cacc[n] += __shfl_xor(cacc[n], msk, 64);
  if (quad == 0)
#pragma unroll
    for (int n = 0; n < 4; ++n)
      atomicAdd(&red_col[wc * 64 + n * 16 + l15], cacc[n]);

  __syncthreads();
  if (tid < BM) atomicAdd(&rowsum[bi * BM + tid], red_row[tid]);
  else          atomicAdd(&colsum[bj * BM + (tid - BM)], red_col[tid - BM]);
}

// ============================ FALLBACK PATH (R1, known-good) ================
__global__ __launch_bounds__(256) void norm_kernel(const float* __restrict__ x,
                                                   const float* __restrict__ y,
                                                   float* __restrict__ invn) {
  int wid  = (int)((blockIdx.x * blockDim.x + threadIdx.x) >> 6);
  int lane = threadIdx.x & 63;
  const float* src = (wid < NROWS) ? x : y;
  int row = (wid < NROWS) ? wid : (wid - NROWS);
  const float4* p = (const float4*)(src + (size_t)row * DDIM);
  float s = 0.f;
#pragma unroll
  for (int a = 0; a < 4; ++a) {
    float4 v = p[a * 64 + lane];
    s = fmaf(v.x, v.x, s); s = fmaf(v.y, v.y, s);
    s = fmaf(v.z, v.z, s); s = fmaf(v.w, v.w, s);
  }
#pragma unroll
  for (int m = 1; m < 64; m <<= 1) s += __shfl_xor(s, m, 64);
  if (lane == 0) invn[wid] = 1.0f / fmaxf(sqrtf(s), 1e-8f);
}

__global__ __launch_bounds__(256) void gemm_kernel(const float* __restrict__ x,
                                                   const float* __restrict__ y,
                                                   const float* __restrict__ invn,
                                                   float* __restrict__ rowsum,
                                                   float* __restrict__ colsum,
                                                   float* __restrict__ diagv) {
  __shared__ alignas(16) unsigned short As[BT * 64];
  __shared__ alignas(16) unsigned short Bs[BT * 64];
  __shared__ float red_row[BT];
  __shared__ float red_col[BT];

  const int tid  = threadIdx.x;
  const int bi   = blockIdx.y;
  const int bj   = blockIdx.x;
  const int lane = tid & 63;
  const int wave = tid >> 6;
  const int wr   = wave >> 1, wc = wave & 1;
  const int quad = lane >> 4, l15 = lane & 15;
  const int srow = tid >> 4;
  const int sc4  = tid & 15;

  if (tid < BT) red_row[tid] = 0.f; else red_col[tid - BT] = 0.f;

  float ainv[8], binv[8];
#pragma unroll
  for (int a = 0; a < 8; ++a) {
    ainv[a] = invn[bi * BT + a * 16 + srow];
    binv[a] = invn[NROWS + bj * BT + a * 16 + srow];
  }

  f32x4 acc[4][4];
#pragma unroll
  for (int i = 0; i < 4; ++i)
#pragma unroll
    for (int j = 0; j < 4; ++j) acc[i][j] = (f32x4){0.f, 0.f, 0.f, 0.f};

  for (int k0 = 0; k0 < DDIM; k0 += 64) {
#pragma unroll
    for (int a = 0; a < 8; ++a) {
      int row = a * 16 + srow;
      float4 va = *(const float4*)(x + (size_t)(bi * BT + row) * DDIM + k0 + sc4 * 4);
      float4 vb = *(const float4*)(y + (size_t)(bj * BT + row) * DDIM + k0 + sc4 * 4);
      float sa = ainv[a], sb = binv[a];
      unsigned long long pa =
          (unsigned long long)f2bf_bits(va.x * sa) |
          ((unsigned long long)f2bf_bits(va.y * sa) << 16) |
          ((unsigned long long)f2bf_bits(va.z * sa) << 32) |
          ((unsigned long long)f2bf_bits(va.w * sa) << 48);
      unsigned long long pb =
          (unsigned long long)f2bf_bits(vb.x * sb) |
          ((unsigned long long)f2bf_bits(vb.y * sb) << 16) |
          ((unsigned long long)f2bf_bits(vb.z * sb) << 32) |
          ((unsigned long long)f2bf_bits(vb.w * sb) << 48);
      *(unsigned long long*)&As[row * 64 + sc4 * 4] = pa;
      *(unsigned long long*)&Bs[row * 64 + sc4 * 4] = pb;
    }
    __syncthreads();
#pragma unroll
    for (int kk = 0; kk < 64; kk += 32) {
      bf16x8 af[4], bf[4];
#pragma unroll
      for (int f = 0; f < 4; ++f) {
        af[f] = *(const bf16x8*)&As[(wr * 64 + f * 16 + l15) * 64 + kk + quad * 8];
        bf[f] = *(const bf16x8*)&Bs[(wc * 64 + f * 16 + l15) * 64 + kk + quad * 8];
      }
#pragma unroll
      for (int fr = 0; fr < 4; ++fr)
#pragma unroll
        for (int fc = 0; fc < 4; ++fc)
          acc[fr][fc] = __builtin_amdgcn_mfma_f32_16x16x32_bf16(af[fr], bf[fc], acc[fr][fc], 0, 0, 0);
    }
    __syncthreads();
  }

  if (bi == bj && wr == wc && (l15 >> 2) == quad) {
    int r = l15 & 3;
#pragma unroll
    for (int f = 0; f < 4; ++f)
      diagv[bi * BT + wr * 64 + f * 16 + l15] = acc[f][f][r];
  }

  float racc[4][4];
  float cacc[4];
#pragma unroll
  for (int i = 0; i < 4; ++i) {
    cacc[i] = 0.f;
#pragma unroll
    for (int j = 0; j < 4; ++j) racc[i][j] = 0.f;
  }
#pragma unroll
  for (int fr = 0; fr < 4; ++fr)
#pragma unroll
    for (int fc = 0; fc < 4; ++fc) {
      f32x4 v = acc[fr][fc];
#pragma unroll
      for (int r = 0; r < 4; ++r) {
        float e = __expf(v[r]);
        racc[fr][r] += e;
        cacc[fc]    += e;
      }
    }
#pragma unroll
  for (int m = 1; m <= 8; m <<= 1)
#pragma unroll
    for (int fr = 0; fr < 4; ++fr)
#pragma unroll
      for (int r = 0; r < 4; ++r) racc[fr][r] += __shfl_xor(racc[fr][r], m, 64);
  if (l15 == 0)
#pragma unroll
    for (int fr = 0; fr < 4; ++fr)
#pragma unroll
      for (int r = 0; r < 4; ++r)
        atomicAdd(&red_row[wr * 64 + fr * 16 + quad * 4 + r], racc[fr][r]);
#pragma unroll
  for (int m = 16; m <= 32; m <<= 1)
#pragma unroll
    for (int fc = 0; fc < 4; ++fc) cacc[fc] += __shfl_xor(cacc[fc], m, 64);
  if (quad == 0)
#pragma unroll
    for (int fc = 0; fc < 4; ++fc)
      atomicAdd(&red_col[wc * 64 + fc * 16 + l15], cacc[fc]);

  __syncthreads();
  if (tid < BT) atomicAdd(&rowsum[bi * BT + tid], red_row[tid]);
  else          atomicAdd(&colsum[bj * BT + (tid - BT)], red_col[tid - BT]);
}

// ---------------- Final loss (shared by both paths) -------------------------
__global__ __launch_bounds__(1024) void finalize_kernel(const float* __restrict__ rowsum,
                                                        const float* __restrict__ colsum,
                                                        const float* __restrict__ diagv,
                                                        float* __restrict__ out) {
  float s = 0.f;
  for (int i = threadIdx.x; i < NROWS; i += 1024) {
    float d  = diagv[i];
    float ed = __expf(d);
    float m1 = __expf(d - MARGIN);
    float negR = rowsum[i] - ed;
    float negC = colsum[i] - ed;
    s += __logf((m1 + negR) / m1) + __logf((m1 + negC) / m1);
  }
  __shared__ float red[16];
#pragma unroll
  for (int m = 1; m < 64; m <<= 1) s += __shfl_xor(s, m, 64);
  if ((threadIdx.x & 63) == 0) red[threadIdx.x >> 6] = s;
  __syncthreads();
  if (threadIdx.x < 64) {
    float v = (threadIdx.x < 16) ? red[threadIdx.x] : 0.f;
#pragma unroll
    for (int m = 1; m < 16; m <<= 1) v += __shfl_xor(v, m, 64);
    if (threadIdx.x == 0) out[0] = v / (float)NROWS;
  }
}

extern "C" void kernel_launch(void* const* d_in, const int* in_sizes, int n_in,
                              void* d_out, int out_size, void* d_ws, size_t ws_size,
                              hipStream_t stream) {
  const float* x = (const float*)d_in[0];
  const float* y = (const float*)d_in[1];
  float* out = (float*)d_out;
  char* ws = (char*)d_ws;

  const size_t q_bytes = (size_t)NROWS * 512;                // 4 MB each (fp4)
  const size_t need_fast = 2 * q_bytes + 3 * NROWS * 4;      // ~8 MB + 96 KB

  if (ws_size >= need_fast) {
    unsigned short* xq4 = (unsigned short*)ws;
    unsigned short* yq4 = (unsigned short*)(ws + q_bytes);
    float* rowsum = (float*)(ws + 2 * q_bytes);
    float* colsum = rowsum + NROWS;
    float* diagv  = colsum + NROWS;
    normconv4_kernel<<<dim3((2 * NROWS) / 4), 256, 0, stream>>>(x, y, xq4, yq4, rowsum);
    gemm_mx4_kernel<<<dim3(NBLK2, NBLK2), 512, 0, stream>>>(
        (const unsigned char*)xq4, (const unsigned char*)yq4, rowsum, colsum, diagv);
    finalize_kernel<<<dim3(1), 1024, 0, stream>>>(rowsum, colsum, diagv, out);
  } else {
    float* invn   = (float*)ws;
    float* rowsum = (float*)(ws + 16384 * 4);
    float* colsum = rowsum + NROWS;
    float* diagv  = colsum + NROWS;
    hipMemsetAsync(rowsum, 0, 2 * NROWS * sizeof(float), stream);
    norm_kernel<<<dim3((2 * NROWS) / 4 / 64), 256, 0, stream>>>(x, y, invn);
    gemm_kernel<<<dim3(NROWS / BT, NROWS / BT), 256, 0, stream>>>(x, y, invn, rowsum, colsum, diagv);
    finalize_kernel<<<dim3(1), 1024, 0, stream>>>(rowsum, colsum, diagv, out);
  }
}

// Round 17
// 159.427 us; speedup vs baseline: 2.8323x; 2.8323x over previous
//
#include <hip/hip_runtime.h>
#include <hip/hip_bf16.h>
#include <math.h>

#define NROWS 8192
#define DDIM  1024
#define BT    128
#define NBLK  (NROWS / BT)
#define BM    256
#define NBLK2 (NROWS / BM)
#define MARGIN 0.3f
#define INV1024 0.0009765625f

typedef __attribute__((ext_vector_type(4))) float  f32x4;
typedef __attribute__((ext_vector_type(8))) __bf16 bf16x8;
typedef __attribute__((ext_vector_type(4))) int    i32x4;
typedef __attribute__((ext_vector_type(8))) int    i32x8;

__device__ __forceinline__ unsigned f2bf_bits(float f) {
  unsigned u = __float_as_uint(f);
  u += 0x7fffu + ((u >> 16) & 1u);   // RNE
  return u >> 16;
}

// fp4 e2m1 quantize of u (|u| up to ~6, saturating): 3-bit magnitude code is
// monotonic over levels {0,0.5,1,1.5,2,3,4,6} -> compare ladder.
__device__ __forceinline__ unsigned q4(float u) {
  float a = fabsf(u);
  unsigned c = (unsigned)(a > 0.25f) + (unsigned)(a > 0.75f) + (unsigned)(a > 1.25f)
             + (unsigned)(a > 1.75f) + (unsigned)(a > 2.5f)  + (unsigned)(a > 3.5f)
             + (unsigned)(a > 5.0f);
  return c | ((__float_as_uint(u) >> 28) & 8u);   // sign -> bit 3
}

// ============================ FAST PATH (MX-fp4) ============================
// Kernel A: row-norm + fp4 e2m1 quantize of 32*xn (row-major, 512 B/row);
// zeroes rowsum/colsum.
__global__ __launch_bounds__(256) void normconv4_kernel(const float* __restrict__ x,
                                                        const float* __restrict__ y,
                                                        unsigned short* __restrict__ xq4,
                                                        unsigned short* __restrict__ yq4,
                                                        float* __restrict__ zero_base) {
  if (blockIdx.x < 16) {  // 16 blk * 256 thr * float4 = 16384 floats (rowsum+colsum)
    ((float4*)zero_base)[blockIdx.x * 256 + threadIdx.x] = (float4){0.f, 0.f, 0.f, 0.f};
  }
  int wid  = blockIdx.x * 4 + (threadIdx.x >> 6);   // one wave per row
  int lane = threadIdx.x & 63;
  bool isx = (wid < NROWS);
  const float* src = isx ? x : y;
  unsigned short* dst = isx ? xq4 : yq4;
  int row = isx ? wid : (wid - NROWS);
  const float4* p = (const float4*)(src + (size_t)row * DDIM);
  float4 v[4];
  float s = 0.f;
#pragma unroll
  for (int a = 0; a < 4; ++a) {
    v[a] = p[a * 64 + lane];
    s = fmaf(v[a].x, v[a].x, s); s = fmaf(v[a].y, v[a].y, s);
    s = fmaf(v[a].z, v[a].z, s); s = fmaf(v[a].w, v[a].w, s);
  }
#pragma unroll
  for (int m = 1; m < 64; m <<= 1) s += __shfl_xor(s, m, 64);
  float inv = 32.0f / fmaxf(sqrtf(s), 1e-8f);
  unsigned short* drow = dst + (size_t)row * 256;  // 512 B/row as ushort
#pragma unroll
  for (int a = 0; a < 4; ++a) {
    unsigned n0 = q4(v[a].x * inv), n1 = q4(v[a].y * inv);
    unsigned n2 = q4(v[a].z * inv), n3 = q4(v[a].w * inv);
    drow[a * 64 + lane] = (unsigned short)(n0 | (n1 << 4) | (n2 << 8) | (n3 << 12));
  }
}

// Kernel B: MX-fp4 GEMM, R16: 256x256 tile, **16 waves (4Mx4N, 1024 thr)**,
// per-wave 64x64 -> acc[4][4] = 64 regs. R14/R15 proved the allocator caps a
// 512-thread block at ~112 arch VGPRs REGARDLESS of launch_bounds (both
// (512,2) and (512,1) gave VGPR_Count=112 + 2.36 GB accumulator spill).
// Fix the FOOTPRINT, not the hint: 64-reg accumulator is R13's measured
// no-spill profile (VGPR_Count=64). Schedule is the R14 structure (absmax=0
// proven) transposed: per K-tile 4 phases of {1xA ds_read (+4xB at p0) |
// DMA issue (A@p0, B@p2) -> barrier -> setprio(1) -> 4 MFMA -> setprio(0)
// -> [p3: counted vmcnt(2)] -> barrier}; 3 LDS buffers (96 KB), depth-2
// pipeline; each wave stages 16 A-rows + 16 B-rows (2 DMAs/tile).
// 16 waves = 4 waves/SIMD (50% occ); budget 64 acc + ~54 operand/addr < 128.
__global__ __launch_bounds__(1024, 1) void gemm_mx4_kernel(const unsigned char* __restrict__ xq4,
                                                           const unsigned char* __restrict__ yq4,
                                                           float* __restrict__ rowsum,
                                                           float* __restrict__ colsum,
                                                           float* __restrict__ diagv) {
  __shared__ alignas(16) unsigned char As[3][BM * 64];  // 3 x 16 KB
  __shared__ alignas(16) unsigned char Bs[3][BM * 64];  // 3 x 16 KB
  __shared__ float red_row[BM];
  __shared__ float red_col[BM];

  const int tid  = threadIdx.x;
  const int bi   = blockIdx.y;
  const int bj   = blockIdx.x;
  const int lane = tid & 63;
  const int wave = tid >> 6;            // 0..15
  const int wr   = wave >> 2, wc = wave & 3;   // 4 x 4 wave grid
  const int quad = lane >> 4, l15 = lane & 15;

  if (tid < BM) red_row[tid] = 0.f;
  else if (tid < 2 * BM) red_col[tid - BM] = 0.f;

  // staging (R10-proven pattern): one 1024-B DMA covers 16 rows x 64 B;
  // lane l -> local row (l>>2), physical group (l&3); SOURCE logical group
  // (l&3)^((l>>3)&3). Each wave stages A rows [wave*16, wave*16+16) + same B.
  const int r_l = lane >> 2;
  const int cg  = (lane & 3) ^ ((lane >> 3) & 3);
  const unsigned char* ga = xq4 + (size_t)(bi * BM + wave * 16 + r_l) * 512 + cg * 16;
  const unsigned char* gb = yq4 + (size_t)(bj * BM + wave * 16 + r_l) * 512 + cg * 16;

#define DMA_A(buf, kb)                                                          \
  __builtin_amdgcn_global_load_lds(                                             \
      (const __attribute__((address_space(1))) unsigned int*)(ga + (kb)),       \
      (__attribute__((address_space(3))) unsigned int*)&As[buf][(wave * 16) * 64], \
      16, 0, 0)
#define DMA_B(buf, kb)                                                          \
  __builtin_amdgcn_global_load_lds(                                             \
      (const __attribute__((address_space(1))) unsigned int*)(gb + (kb)),       \
      (__attribute__((address_space(3))) unsigned int*)&Bs[buf][(wave * 16) * 64], \
      16, 0, 0)

  f32x4 acc[4][4];
#pragma unroll
  for (int i = 0; i < 4; ++i)
#pragma unroll
    for (int j = 0; j < 4; ++j) acc[i][j] = (f32x4){0.f, 0.f, 0.f, 0.f};

  const int pg = (quad ^ ((l15 >> 1) & 3)) * 16;   // physical 16B-group offset

  // prologue: tile0 -> buf0, tile1 -> buf1 (4 DMAs/wave); retire tile0's 2.
  DMA_A(0, 0);  DMA_B(0, 0);
  DMA_A(1, 64); DMA_B(1, 64);
  asm volatile("s_waitcnt vmcnt(2) lgkmcnt(0)" ::: "memory");
  __builtin_amdgcn_s_barrier();

#pragma unroll
  for (int t = 0; t < 8; ++t) {
    const int cur = t % 3;
    const int nb  = (t + 2) % 3;
    const int kb2 = (t + 2) * 64;
    i32x4 b4[4];
#pragma unroll
    for (int p = 0; p < 4; ++p) {
      // phase ds_reads: A frag m=p (+ all 4 B frags at p0)
      i32x4 a0 = *(const i32x4*)&As[cur][(wr * 64 + p * 16 + l15) * 64 + pg];
      if (p == 0) {
#pragma unroll
        for (int n = 0; n < 4; ++n)
          b4[n] = *(const i32x4*)&Bs[cur][(wc * 64 + n * 16 + l15) * 64 + pg];
      }
      // depth-2 pipeline: stage tile t+2 (A at p0, B at p2)
      if (t < 6) {
        if      (p == 0) DMA_A(nb, kb2);
        else if (p == 2) DMA_B(nb, kb2);
      }
      __builtin_amdgcn_s_barrier();
      __builtin_amdgcn_s_setprio(1);
      i32x8 af0 = (i32x8){a0.x, a0.y, a0.z, a0.w, 0, 0, 0, 0};
#pragma unroll
      for (int n = 0; n < 4; ++n) {
        i32x8 bf = (i32x8){b4[n].x, b4[n].y, b4[n].z, b4[n].w, 0, 0, 0, 0};
        acc[p][n] = __builtin_amdgcn_mfma_scale_f32_16x16x128_f8f6f4(
            af0, bf, acc[p][n], 4, 4, 0, 0x7F7F7F7F, 0, 0x7F7F7F7F);
      }
      __builtin_amdgcn_s_setprio(0);
      if (p == 3) {
        // counted: retire tile t+1's 2 DMAs (oldest); keep tile t+2's riding.
        if (t < 6)       asm volatile("s_waitcnt vmcnt(2)" ::: "memory");
        else if (t == 6) asm volatile("s_waitcnt vmcnt(0)" ::: "memory");
        // t==7: nothing outstanding
      }
      __builtin_amdgcn_s_barrier();
    }
  }
#undef DMA_A
#undef DMA_B

  __syncthreads();   // red_* init + all LDS traffic settled before epilogue

  // ---- epilogue (R1-validated frag mapping: row=quad*4+r, col=l15) --------
  // diag: rows wr*64+m*16+(quad*4+r), cols wc*64+n*16+l15; row==col with
  // l15==quad*4+r requires n = 4*(wr-wc)+m -> only wr==wc waves, n=m.
  if (bi == bj && wr == wc && (l15 >> 2) == quad) {
    int r = l15 & 3;
#pragma unroll
    for (int m = 0; m < 4; ++m)
      diagv[bi * BM + wr * 64 + m * 16 + l15] = acc[m][m][r] * INV1024;
  }

  float racc[4][4];
  float cacc[4];
#pragma unroll
  for (int i = 0; i < 4; ++i) {
    cacc[i] = 0.f;
#pragma unroll
    for (int j = 0; j < 4; ++j) racc[i][j] = 0.f;
  }
#pragma unroll
  for (int m = 0; m < 4; ++m)
#pragma unroll
    for (int n = 0; n < 4; ++n) {
      f32x4 v = acc[m][n];
#pragma unroll
      for (int r = 0; r < 4; ++r) {
        float e = __expf(v[r] * INV1024);
        racc[m][r] += e;
        cacc[n]    += e;
      }
    }
  // row partials: reduce over l15 (cols) via masks 1..8
#pragma unroll
  for (int msk = 1; msk <= 8; msk <<= 1)
#pragma unroll
    for (int m = 0; m < 4; ++m)
#pragma unroll
      for (int r = 0; r < 4; ++r) racc[m][r] += __shfl_xor(racc[m][r], msk, 64);
  if (l15 == 0)
#pragma unroll
    for (int m = 0; m < 4; ++m)
#pragma unroll
      for (int r = 0; r < 4; ++r)
        atomicAdd(&red_row[wr * 64 + m * 16 + quad * 4 + r], racc[m][r]);
  // col partials: reduce over quad (rows) via masks 16,32
#pragma unroll
  for (int msk = 16; msk <= 32; msk <<= 1)
#pragma unroll
    for (int n = 0; n < 4; ++n) cacc[n] += __shfl_xor(cacc[n], msk, 64);
  if (quad == 0)
#pragma unroll
    for (int n = 0; n < 4; ++n)
      atomicAdd(&red_col[wc * 64 + n * 16 + l15], cacc[n]);

  __syncthreads();
  if (tid < BM)          atomicAdd(&rowsum[bi * BM + tid], red_row[tid]);
  else if (tid < 2 * BM) atomicAdd(&colsum[bj * BM + (tid - BM)], red_col[tid - BM]);
}

// ============================ FALLBACK PATH (R1, known-good) ================
__global__ __launch_bounds__(256) void norm_kernel(const float* __restrict__ x,
                                                   const float* __restrict__ y,
                                                   float* __restrict__ invn) {
  int wid  = (int)((blockIdx.x * blockDim.x + threadIdx.x) >> 6);
  int lane = threadIdx.x & 63;
  const float* src = (wid < NROWS) ? x : y;
  int row = (wid < NROWS) ? wid : (wid - NROWS);
  const float4* p = (const float4*)(src + (size_t)row * DDIM);
  float s = 0.f;
#pragma unroll
  for (int a = 0; a < 4; ++a) {
    float4 v = p[a * 64 + lane];
    s = fmaf(v.x, v.x, s); s = fmaf(v.y, v.y, s);
    s = fmaf(v.z, v.z, s); s = fmaf(v.w, v.w, s);
  }
#pragma unroll
  for (int m = 1; m < 64; m <<= 1) s += __shfl_xor(s, m, 64);
  if (lane == 0) invn[wid] = 1.0f / fmaxf(sqrtf(s), 1e-8f);
}

__global__ __launch_bounds__(256) void gemm_kernel(const float* __restrict__ x,
                                                   const float* __restrict__ y,
                                                   const float* __restrict__ invn,
                                                   float* __restrict__ rowsum,
                                                   float* __restrict__ colsum,
                                                   float* __restrict__ diagv) {
  __shared__ alignas(16) unsigned short As[BT * 64];
  __shared__ alignas(16) unsigned short Bs[BT * 64];
  __shared__ float red_row[BT];
  __shared__ float red_col[BT];

  const int tid  = threadIdx.x;
  const int bi   = blockIdx.y;
  const int bj   = blockIdx.x;
  const int lane = tid & 63;
  const int wave = tid >> 6;
  const int wr   = wave >> 1, wc = wave & 1;
  const int quad = lane >> 4, l15 = lane & 15;
  const int srow = tid >> 4;
  const int sc4  = tid & 15;

  if (tid < BT) red_row[tid] = 0.f; else red_col[tid - BT] = 0.f;

  float ainv[8], binv[8];
#pragma unroll
  for (int a = 0; a < 8; ++a) {
    ainv[a] = invn[bi * BT + a * 16 + srow];
    binv[a] = invn[NROWS + bj * BT + a * 16 + srow];
  }

  f32x4 acc[4][4];
#pragma unroll
  for (int i = 0; i < 4; ++i)
#pragma unroll
    for (int j = 0; j < 4; ++j) acc[i][j] = (f32x4){0.f, 0.f, 0.f, 0.f};

  for (int k0 = 0; k0 < DDIM; k0 += 64) {
#pragma unroll
    for (int a = 0; a < 8; ++a) {
      int row = a * 16 + srow;
      float4 va = *(const float4*)(x + (size_t)(bi * BT + row) * DDIM + k0 + sc4 * 4);
      float4 vb = *(const float4*)(y + (size_t)(bj * BT + row) * DDIM + k0 + sc4 * 4);
      float sa = ainv[a], sb = binv[a];
      unsigned long long pa =
          (unsigned long long)f2bf_bits(va.x * sa) |
          ((unsigned long long)f2bf_bits(va.y * sa) << 16) |
          ((unsigned long long)f2bf_bits(va.z * sa) << 32) |
          ((unsigned long long)f2bf_bits(va.w * sa) << 48);
      unsigned long long pb =
          (unsigned long long)f2bf_bits(vb.x * sb) |
          ((unsigned long long)f2bf_bits(vb.y * sb) << 16) |
          ((unsigned long long)f2bf_bits(vb.z * sb) << 32) |
          ((unsigned long long)f2bf_bits(vb.w * sb) << 48);
      *(unsigned long long*)&As[row * 64 + sc4 * 4] = pa;
      *(unsigned long long*)&Bs[row * 64 + sc4 * 4] = pb;
    }
    __syncthreads();
#pragma unroll
    for (int kk = 0; kk < 64; kk += 32) {
      bf16x8 af[4], bf[4];
#pragma unroll
      for (int f = 0; f < 4; ++f) {
        af[f] = *(const bf16x8*)&As[(wr * 64 + f * 16 + l15) * 64 + kk + quad * 8];
        bf[f] = *(const bf16x8*)&Bs[(wc * 64 + f * 16 + l15) * 64 + kk + quad * 8];
      }
#pragma unroll
      for (int fr = 0; fr < 4; ++fr)
#pragma unroll
        for (int fc = 0; fc < 4; ++fc)
          acc[fr][fc] = __builtin_amdgcn_mfma_f32_16x16x32_bf16(af[fr], bf[fc], acc[fr][fc], 0, 0, 0);
    }
    __syncthreads();
  }

  if (bi == bj && wr == wc && (l15 >> 2) == quad) {
    int r = l15 & 3;
#pragma unroll
    for (int f = 0; f < 4; ++f)
      diagv[bi * BT + wr * 64 + f * 16 + l15] = acc[f][f][r];
  }

  float racc[4][4];
  float cacc[4];
#pragma unroll
  for (int i = 0; i < 4; ++i) {
    cacc[i] = 0.f;
#pragma unroll
    for (int j = 0; j < 4; ++j) racc[i][j] = 0.f;
  }
#pragma unroll
  for (int fr = 0; fr < 4; ++fr)
#pragma unroll
    for (int fc = 0; fc < 4; ++fc) {
      f32x4 v = acc[fr][fc];
#pragma unroll
      for (int r = 0; r < 4; ++r) {
        float e = __expf(v[r]);
        racc[fr][r] += e;
        cacc[fc]    += e;
      }
    }
#pragma unroll
  for (int m = 1; m <= 8; m <<= 1)
#pragma unroll
    for (int fr = 0; fr < 4; ++fr)
#pragma unroll
      for (int r = 0; r < 4; ++r) racc[fr][r] += __shfl_xor(racc[fr][r], m, 64);
  if (l15 == 0)
#pragma unroll
    for (int fr = 0; fr < 4; ++fr)
#pragma unroll
      for (int r = 0; r < 4; ++r)
        atomicAdd(&red_row[wr * 64 + fr * 16 + quad * 4 + r], racc[fr][r]);
#pragma unroll
  for (int m = 16; m <= 32; m <<= 1)
#pragma unroll
    for (int fc = 0; fc < 4; ++fc) cacc[fc] += __shfl_xor(cacc[fc], m, 64);
  if (quad == 0)
#pragma unroll
    for (int fc = 0; fc < 4; ++fc)
      atomicAdd(&red_col[wc * 64 + fc * 16 + l15], cacc[fc]);

  __syncthreads();
  if (tid < BT) atomicAdd(&rowsum[bi * BT + tid], red_row[tid]);
  else          atomicAdd(&colsum[bj * BT + (tid - BT)], red_col[tid - BT]);
}

// ---------------- Final loss (shared by both paths) -------------------------
__global__ __launch_bounds__(1024) void finalize_kernel(const float* __restrict__ rowsum,
                                                        const float* __restrict__ colsum,
                                                        const float* __restrict__ diagv,
                                                        float* __restrict__ out) {
  float s = 0.f;
  for (int i = threadIdx.x; i < NROWS; i += 1024) {
    float d  = diagv[i];
    float ed = __expf(d);
    float m1 = __expf(d - MARGIN);
    float negR = rowsum[i] - ed;
    float negC = colsum[i] - ed;
    s += __logf((m1 + negR) / m1) + __logf((m1 + negC) / m1);
  }
  __shared__ float red[16];
#pragma unroll
  for (int m = 1; m < 64; m <<= 1) s += __shfl_xor(s, m, 64);
  if ((threadIdx.x & 63) == 0) red[threadIdx.x >> 6] = s;
  __syncthreads();
  if (threadIdx.x < 64) {
    float v = (threadIdx.x < 16) ? red[threadIdx.x] : 0.f;
#pragma unroll
    for (int m = 1; m < 16; m <<= 1) v += __shfl_xor(v, m, 64);
    if (threadIdx.x == 0) out[0] = v / (float)NROWS;
  }
}

extern "C" void kernel_launch(void* const* d_in, const int* in_sizes, int n_in,
                              void* d_out, int out_size, void* d_ws, size_t ws_size,
                              hipStream_t stream) {
  const float* x = (const float*)d_in[0];
  const float* y = (const float*)d_in[1];
  float* out = (float*)d_out;
  char* ws = (char*)d_ws;

  const size_t q_bytes = (size_t)NROWS * 512;                // 4 MB each (fp4)
  const size_t need_fast = 2 * q_bytes + 3 * NROWS * 4;      // ~8 MB + 96 KB

  if (ws_size >= need_fast) {
    unsigned short* xq4 = (unsigned short*)ws;
    unsigned short* yq4 = (unsigned short*)(ws + q_bytes);
    float* rowsum = (float*)(ws + 2 * q_bytes);
    float* colsum = rowsum + NROWS;
    float* diagv  = colsum + NROWS;
    normconv4_kernel<<<dim3((2 * NROWS) / 4), 256, 0, stream>>>(x, y, xq4, yq4, rowsum);
    gemm_mx4_kernel<<<dim3(NBLK2, NBLK2), 1024, 0, stream>>>(
        (const unsigned char*)xq4, (const unsigned char*)yq4, rowsum, colsum, diagv);
    finalize_kernel<<<dim3(1), 1024, 0, stream>>>(rowsum, colsum, diagv, out);
  } else {
    float* invn   = (float*)ws;
    float* rowsum = (float*)(ws + 16384 * 4);
    float* colsum = rowsum + NROWS;
    float* diagv  = colsum + NROWS;
    hipMemsetAsync(rowsum, 0, 2 * NROWS * sizeof(float), stream);
    norm_kernel<<<dim3((2 * NROWS) / 4 / 64), 256, 0, stream>>>(x, y, invn);
    gemm_kernel<<<dim3(NROWS / BT, NROWS / BT), 256, 0, stream>>>(x, y, invn, rowsum, colsum, diagv);
    finalize_kernel<<<dim3(1), 1024, 0, stream>>>(rowsum, colsum, diagv, out);
  }
}